// Round 2
// baseline (24.131 us; speedup 1.0000x reference)
//
#include <hip/hip_runtime.h>

// ColorTransform: per-pixel degree-3 polynomial feature expansion (19 monomials
// of 3 channels) followed by a 19->3 linear map + bias.
// x: [B=16, C=3, H=512, W=512] f32; weight: [19,3] f32; bias: [3] f32.
// Memory-bound: ~100 MB traffic -> ~16 us floor at 6.3 TB/s.
// R1: 21.5 us (4.7 TB/s eff). R2: one-shot grid (no grid-stride loop) +
// nontemporal loads/stores (touch-once streams, skip cache allocate).

constexpr int HW = 512 * 512;          // pixels per (b, c) plane
constexpr int LOG2_HW = 18;

typedef float v4f __attribute__((ext_vector_type(4)));

__device__ __forceinline__ float rfl(float v) {
    // Force a wave-uniform value into an SGPR (keeps the 57 weights + 3 bias
    // out of the VGPR budget; v_fma can take one SGPR operand).
    return __uint_as_float(__builtin_amdgcn_readfirstlane(__float_as_uint(v)));
}

__global__ __launch_bounds__(256) void ct_kernel(
    const float* __restrict__ x, const float* __restrict__ wgt,
    const float* __restrict__ bias, float* __restrict__ out, int ngroups)
{
    // Uniform (scalar) copies of the 19x3 weight matrix + bias.
    float w[57];
#pragma unroll
    for (int i = 0; i < 57; ++i) w[i] = rfl(wgt[i]);
    const float b0 = rfl(bias[0]);
    const float b1 = rfl(bias[1]);
    const float b2 = rfl(bias[2]);

    const int g = blockIdx.x * blockDim.x + threadIdx.x;
    if (g >= ngroups) return;

    const int p  = g << 2;               // flat pixel index (4 px / thread)
    const int b  = p >> LOG2_HW;         // batch index (HW = 2^18)
    const int hw = p & (HW - 1);

    const float* base = x + (size_t)b * 3 * HW + hw;
    v4f v0 = __builtin_nontemporal_load(reinterpret_cast<const v4f*>(base));
    v4f v1 = __builtin_nontemporal_load(reinterpret_cast<const v4f*>(base + HW));
    v4f v2 = __builtin_nontemporal_load(reinterpret_cast<const v4f*>(base + 2 * HW));

    v4f o0, o1, o2;
#pragma unroll
    for (int j = 0; j < 4; ++j) {
        const float a = v0[j], bch = v1[j], c = v2[j];
        // 19 monomials, exact reference order & association:
        float f[19];
        f[0]  = a;          f[1]  = bch;        f[2]  = c;
        f[3]  = a * a;      f[4]  = a * bch;    f[5]  = a * c;
        f[6]  = bch * bch;  f[7]  = bch * c;    f[8]  = c * c;
        f[9]  = a * f[3];   f[10] = a * f[4];   f[11] = a * f[5];
        f[12] = a * f[6];   f[13] = a * f[7];   f[14] = a * f[8];
        f[15] = bch * f[6]; f[16] = bch * f[7]; f[17] = bch * f[8];
        f[18] = c * f[8];

        float s0 = b0, s1 = b1, s2 = b2;
#pragma unroll
        for (int k = 0; k < 19; ++k) {
            s0 = fmaf(f[k], w[3 * k + 0], s0);
            s1 = fmaf(f[k], w[3 * k + 1], s1);
            s2 = fmaf(f[k], w[3 * k + 2], s2);
        }
        o0[j] = s0; o1[j] = s1; o2[j] = s2;
    }

    float* obase = out + (size_t)b * 3 * HW + hw;
    __builtin_nontemporal_store(o0, reinterpret_cast<v4f*>(obase));
    __builtin_nontemporal_store(o1, reinterpret_cast<v4f*>(obase + HW));
    __builtin_nontemporal_store(o2, reinterpret_cast<v4f*>(obase + 2 * HW));
}

extern "C" void kernel_launch(void* const* d_in, const int* in_sizes, int n_in,
                              void* d_out, int out_size, void* d_ws, size_t ws_size,
                              hipStream_t stream) {
    const float* x    = (const float*)d_in[0];   // [16,3,512,512]
    const float* wgt  = (const float*)d_in[1];   // [19,3]
    const float* bias = (const float*)d_in[2];   // [3]
    // d_in[3] = degree (int, ==3) — baked into the kernel.
    float* out = (float*)d_out;

    const int npix    = in_sizes[0] / 3;         // B*H*W = 4,194,304
    const int ngroups = npix / 4;                // 4 pixels per thread
    const int block   = 256;
    const int grid    = (ngroups + block - 1) / block;  // 4096
    ct_kernel<<<grid, block, 0, stream>>>(x, wgt, bias, out, ngroups);
}

// Round 3
// 22.200 us; speedup vs baseline: 1.0869x; 1.0869x over previous
//
#include <hip/hip_runtime.h>

// ColorTransform: per-pixel degree-3 polynomial feature expansion (19 monomials
// of 3 channels) followed by a 19->3 linear map + bias.
// x: [B=16, C=3, H=512, W=512] f32; weight: [19,3] f32; bias: [3] f32.
// Memory-bound: ~100 MB traffic -> ~16 us floor at ~6.3 TB/s (fills measure 6.8).
// R1: 21.5 us (grid-stride x2, plain loads). R2: nt hints + one-shot = 24.1 us
// REGRESSION -> nt reverted. R3: 8 px/thread one-shot, all 6 dwordx4 loads
// issued up front (2x MLP per thread), plain loads/stores, 2048 blocks.

constexpr int HW = 512 * 512;          // pixels per (b, c) plane
constexpr int LOG2_HW = 18;

typedef float v4f __attribute__((ext_vector_type(4)));

__device__ __forceinline__ float rfl(float v) {
    // Force a wave-uniform value into an SGPR (keeps the 57 weights + 3 bias
    // out of the VGPR budget; v_fma can take one SGPR operand).
    return __uint_as_float(__builtin_amdgcn_readfirstlane(__float_as_uint(v)));
}

__global__ __launch_bounds__(256) void ct_kernel(
    const float* __restrict__ x, const float* __restrict__ wgt,
    const float* __restrict__ bias, float* __restrict__ out, int ngroups)
{
    // Uniform (scalar) copies of the 19x3 weight matrix + bias.
    float w[57];
#pragma unroll
    for (int i = 0; i < 57; ++i) w[i] = rfl(wgt[i]);
    const float b0 = rfl(bias[0]);
    const float b1 = rfl(bias[1]);
    const float b2 = rfl(bias[2]);

    const int g = blockIdx.x * blockDim.x + threadIdx.x;
    if (g >= ngroups) return;

    const int p  = g << 3;               // flat pixel index (8 px / thread)
    const int b  = p >> LOG2_HW;         // batch index (HW = 2^18)
    const int hw = p & (HW - 1);

    const float* base = x + (size_t)b * 3 * HW + hw;
    // Issue all 6 loads before any compute: max memory-level parallelism.
    const v4f va0 = *reinterpret_cast<const v4f*>(base);
    const v4f va1 = *reinterpret_cast<const v4f*>(base + 4);
    const v4f vb0 = *reinterpret_cast<const v4f*>(base + HW);
    const v4f vb1 = *reinterpret_cast<const v4f*>(base + HW + 4);
    const v4f vc0 = *reinterpret_cast<const v4f*>(base + 2 * HW);
    const v4f vc1 = *reinterpret_cast<const v4f*>(base + 2 * HW + 4);

    v4f o00, o01, o10, o11, o20, o21;
#pragma unroll
    for (int j = 0; j < 8; ++j) {
        const float a   = (j < 4) ? va0[j & 3] : va1[j & 3];
        const float bch = (j < 4) ? vb0[j & 3] : vb1[j & 3];
        const float c   = (j < 4) ? vc0[j & 3] : vc1[j & 3];
        // 19 monomials, exact reference order & association:
        float f[19];
        f[0]  = a;          f[1]  = bch;        f[2]  = c;
        f[3]  = a * a;      f[4]  = a * bch;    f[5]  = a * c;
        f[6]  = bch * bch;  f[7]  = bch * c;    f[8]  = c * c;
        f[9]  = a * f[3];   f[10] = a * f[4];   f[11] = a * f[5];
        f[12] = a * f[6];   f[13] = a * f[7];   f[14] = a * f[8];
        f[15] = bch * f[6]; f[16] = bch * f[7]; f[17] = bch * f[8];
        f[18] = c * f[8];

        float s0 = b0, s1 = b1, s2 = b2;
#pragma unroll
        for (int k = 0; k < 19; ++k) {
            s0 = fmaf(f[k], w[3 * k + 0], s0);
            s1 = fmaf(f[k], w[3 * k + 1], s1);
            s2 = fmaf(f[k], w[3 * k + 2], s2);
        }
        if (j < 4) { o00[j & 3] = s0; o10[j & 3] = s1; o20[j & 3] = s2; }
        else       { o01[j & 3] = s0; o11[j & 3] = s1; o21[j & 3] = s2; }
    }

    float* obase = out + (size_t)b * 3 * HW + hw;
    *reinterpret_cast<v4f*>(obase)              = o00;
    *reinterpret_cast<v4f*>(obase + 4)          = o01;
    *reinterpret_cast<v4f*>(obase + HW)         = o10;
    *reinterpret_cast<v4f*>(obase + HW + 4)     = o11;
    *reinterpret_cast<v4f*>(obase + 2 * HW)     = o20;
    *reinterpret_cast<v4f*>(obase + 2 * HW + 4) = o21;
}

extern "C" void kernel_launch(void* const* d_in, const int* in_sizes, int n_in,
                              void* d_out, int out_size, void* d_ws, size_t ws_size,
                              hipStream_t stream) {
    const float* x    = (const float*)d_in[0];   // [16,3,512,512]
    const float* wgt  = (const float*)d_in[1];   // [19,3]
    const float* bias = (const float*)d_in[2];   // [3]
    // d_in[3] = degree (int, ==3) — baked into the kernel.
    float* out = (float*)d_out;

    const int npix    = in_sizes[0] / 3;         // B*H*W = 4,194,304
    const int ngroups = npix / 8;                // 8 pixels per thread
    const int block   = 256;
    const int grid    = (ngroups + block - 1) / block;  // 2048
    ct_kernel<<<grid, block, 0, stream>>>(x, wgt, bias, out, ngroups);
}